// Round 5
// baseline (220.225 us; speedup 1.0000x reference)
//
#include <hip/hip_runtime.h>
#include <hip/hip_bf16.h>
#include <cstdint>
#include <math.h>

#define BATCH 4
#define SDIM  2048
#define DDIM  1024
#define QKVN  3072   // fused Q|K|V output width

typedef __attribute__((ext_vector_type(8))) short bf16x8;
typedef __attribute__((ext_vector_type(8))) unsigned short u16x8;
typedef __attribute__((ext_vector_type(4))) float f32x4;

__device__ __forceinline__ float bf2f(unsigned short u) {
  union { unsigned int i; float f; } v; v.i = ((unsigned int)u) << 16; return v.f;
}
__device__ __forceinline__ unsigned short f2bf(float f) {
  unsigned int i = __float_as_uint(f);
  return (unsigned short)((i + 0x7FFFu + ((i >> 16) & 1u)) >> 16);  // RNE
}

#define GLOAD16(gp, lp) \
  __builtin_amdgcn_global_load_lds((const __attribute__((address_space(1))) void*)(gp), \
                                   (__attribute__((address_space(3))) void*)(lp), 16, 0, 0)

// ---------------- fp32 -> bf16 convert (single src) ----------------
__global__ void cvt_f32_bf16(const float* __restrict__ in,
                             unsigned short* __restrict__ out, int n) {
  int i0 = (blockIdx.x * 256 + threadIdx.x) * 4;
  int stride = gridDim.x * 256 * 4;
  for (int i = i0; i < n; i += stride) {
    float4 v = *reinterpret_cast<const float4*>(in + i);
    ushort4 o;
    o.x = f2bf(v.x); o.y = f2bf(v.y); o.z = f2bf(v.z); o.w = f2bf(v.w);
    *reinterpret_cast<ushort4*>(out + i) = o;
  }
}

// 4 weight matrices (1M elems each) in one dispatch; dsts contiguous slabs.
__global__ void cvt_weights(const float* __restrict__ s0, const float* __restrict__ s1,
                            const float* __restrict__ s2, const float* __restrict__ s3,
                            unsigned short* __restrict__ out) {
  const int NW = DDIM * DDIM;
  const float* src = (blockIdx.y == 0) ? s0 : (blockIdx.y == 1) ? s1
                    : (blockIdx.y == 2) ? s2 : s3;
  unsigned short* dst = out + (size_t)blockIdx.y * NW;
  int i0 = (blockIdx.x * 256 + threadIdx.x) * 4;
  int stride = gridDim.x * 256 * 4;
  for (int i = i0; i < NW; i += stride) {
    float4 v = *reinterpret_cast<const float4*>(src + i);
    ushort4 o;
    o.x = f2bf(v.x); o.y = f2bf(v.y); o.z = f2bf(v.z); o.w = f2bf(v.w);
    *reinterpret_cast<ushort4*>(dst + i) = o;
  }
}

// ============ 256x256 8-phase GEMM (faithful m201 geometry), K=1024 ==========
// NT: C[m,n] = sum_k A[m,k]*B[n,k]. 512 thr = 8 waves (2M x 4N); wave out 128x64.
// LDS 128KB: A slabs [dbuf][half] 128r x 64c x 2B = 16KB (half = M-half, = wm);
//            B slabs likewise (half = N-half, wave wn -> half wn>>1).
// Slab swizzle: row r (128B), granule g (16B col): phys p = g ^ (r&7).
//   Stage: linear LDS dest, inverse-swizzled global src (verified R3: 0 conflicts).
// Per K-tile t (dbuf d=t&1), 4 phases, each {ds_read; stage; [vmcnt]; barrier;
//   lgkmcnt(0); 16 MFMA; barrier}:
//   ph0: ks0,mhalf0 (+B ks0 read); stage A(t+1) both halves -> dbuf d^1
//   ph1: ks0,mhalf1
//   ph2: ks1,mhalf0 (+B ks1 read)
//   ph3: ks1,mhalf1; stage B(t+2) both halves -> dbuf d (B(t) free after ph2);
//        wait vmcnt(4) [drains B(t+1)+A(t+1); leaves B(t+2)] -- derived FIFO,
//        edge tiles use vmcnt(0).  Issue-to-drain >= 3 phases for A, 4 for B.
// MODE 0: QKV  A=xb[8192,1024] B=Wqkv[3072,1024] C=bf16[8192,3072]+bias(sel)
// MODE 1: outp A=Ob[8192,1024] B=Wo[1024,1024]   C=f32[8192,1024]+bias
template<int MODE>
__global__ __launch_bounds__(512, 1)
void gemm256(const unsigned short* __restrict__ A,
             const unsigned short* __restrict__ B,
             const float* __restrict__ bias0,
             const float* __restrict__ bias1,
             const float* __restrict__ bias2,
             void* __restrict__ C)
{
  constexpr int NTI = 32;
  constexpr int NTJ = (MODE == 0) ? 12 : 4;
  constexpr int NT  = 16;                 // K / 64
  constexpr int LDK = 1024;
  constexpr int CLD = (MODE == 0) ? QKVN : DDIM;

  __shared__ unsigned short smem[65536];  // 128 KB; A at 0, B at 32768 (shorts)

  // ti-band-per-XCD bijective swizzle: each XCD owns a 4-wide ti band (2MB of A
  // -> fits 4MB XCD L2), walks tj within it.
  const int bid = blockIdx.x;
  const int xcd = bid & 7;
  const int s   = bid >> 3;
  const int ti  = xcd * 4 + (s & 3);      // 0..31
  const int tj  = s >> 2;                 // 0..NTJ-1

  const int tid  = threadIdx.x;
  const int wave = tid >> 6;
  const int lane = tid & 63;
  const int wm   = wave >> 2;             // M half (0..1)
  const int wn   = wave & 3;              // N quarter (0..3)
  const int bh   = wn >> 1;               // B half this wave reads
  const int br0  = (wn & 1) * 64;         // row base within B half-slab

  const unsigned short* At = A + (size_t)ti * 256 * LDK;
  const unsigned short* Bt = B + (size_t)tj * 256 * LDK;

  // staging per-lane source (inverse swizzle; LDS dest stays linear)
  const int lg   = (lane & 7) ^ (lane >> 3);   // logical granule
  const int srow = lane >> 3;                  // row within 8-row gload chunk
  const int scol = lg * 8;                     // elem col within 64-col K-tile

  // fragment read offsets (swizzled): row-in-slab = mbase*16+fr
  const int s_  = lane >> 4;
  const int fr  = lane & 15;
  const int p0  = s_ ^ (fr & 7);
  const int fA0 = fr * 64 + p0 * 8;            // ks=0
  const int fA1 = fr * 64 + (p0 ^ 4) * 8;      // ks=1
  const int fB0 = br0 * 64 + fA0;
  const int fB1 = br0 * 64 + fA1;

  f32x4 acc[8][4];
#pragma unroll
  for (int i = 0; i < 8; ++i)
#pragma unroll
    for (int j = 0; j < 4; ++j) acc[i][j] = (f32x4){0.f, 0.f, 0.f, 0.f};

  bf16x8 bg0, bg1, bg2, bg3;

#define STAGE_A(dd, hh, kt) do {                                                           \
    const unsigned short* sa_ = At + (size_t)((hh) * 128 + 8 * wave + srow) * LDK          \
                                   + (kt) * 64 + scol;                                     \
    unsigned short* da_ = smem + ((dd) * 2 + (hh)) * 8192 + wave * 512;                    \
    GLOAD16(sa_, da_);                                                                     \
    GLOAD16(sa_ + (size_t)64 * LDK, da_ + 4096);                                           \
  } while (0)

#define STAGE_B(dd, hh, kt) do {                                                           \
    const unsigned short* sb_ = Bt + (size_t)((hh) * 128 + 8 * wave + srow) * LDK          \
                                   + (kt) * 64 + scol;                                     \
    unsigned short* db_ = smem + 32768 + ((dd) * 2 + (hh)) * 8192 + wave * 512;            \
    GLOAD16(sb_, db_);                                                                     \
    GLOAD16(sb_ + (size_t)64 * LDK, db_ + 4096);                                           \
  } while (0)

#define PHASE(MG, KS, READB, STG, VMC) do {                                                \
    const unsigned short* As_ = smem + (d * 2 + wm) * 8192;                                \
    bf16x8 af[4];                                                                          \
    _Pragma("unroll")                                                                      \
    for (int mi = 0; mi < 4; ++mi)                                                         \
      af[mi] = *(const bf16x8*)(As_ + ((MG) * 4 + mi) * 1024 + ((KS) ? fA1 : fA0));        \
    if (READB) {                                                                           \
      const unsigned short* Bs_ = smem + 32768 + (d * 2 + bh) * 8192;                      \
      bg0 = *(const bf16x8*)(Bs_ + 0 * 1024 + ((KS) ? fB1 : fB0));                         \
      bg1 = *(const bf16x8*)(Bs_ + 1 * 1024 + ((KS) ? fB1 : fB0));                         \
      bg2 = *(const bf16x8*)(Bs_ + 2 * 1024 + ((KS) ? fB1 : fB0));                         \
      bg3 = *(const bf16x8*)(Bs_ + 3 * 1024 + ((KS) ? fB1 : fB0));                         \
    }                                                                                      \
    STG;                                                                                   \
    VMC;                                                                                   \
    __builtin_amdgcn_s_barrier();                                                          \
    asm volatile("s_waitcnt lgkmcnt(0)" ::: "memory");                                     \
    __builtin_amdgcn_sched_barrier(0);                                                     \
    __builtin_amdgcn_s_setprio(1);                                                         \
    _Pragma("unroll")                                                                      \
    for (int mi = 0; mi < 4; ++mi) {                                                       \
      acc[(MG) * 4 + mi][0] = __builtin_amdgcn_mfma_f32_16x16x32_bf16(af[mi], bg0, acc[(MG) * 4 + mi][0], 0, 0, 0); \
      acc[(MG) * 4 + mi][1] = __builtin_amdgcn_mfma_f32_16x16x32_bf16(af[mi], bg1, acc[(MG) * 4 + mi][1], 0, 0, 0); \
      acc[(MG) * 4 + mi][2] = __builtin_amdgcn_mfma_f32_16x16x32_bf16(af[mi], bg2, acc[(MG) * 4 + mi][2], 0, 0, 0); \
      acc[(MG) * 4 + mi][3] = __builtin_amdgcn_mfma_f32_16x16x32_bf16(af[mi], bg3, acc[(MG) * 4 + mi][3], 0, 0, 0); \
    }                                                                                      \
    __builtin_amdgcn_s_setprio(0);                                                         \
    __builtin_amdgcn_s_barrier();                                                          \
  } while (0)

  // prologue: A(0), B(0), B(1); drain A(0)+B(0), leave B(1)'s 4 loads
  STAGE_A(0, 0, 0); STAGE_A(0, 1, 0);
  STAGE_B(0, 0, 0); STAGE_B(0, 1, 0);
  STAGE_B(1, 0, 1); STAGE_B(1, 1, 1);
  asm volatile("s_waitcnt vmcnt(4)" ::: "memory");
  __builtin_amdgcn_s_barrier();

  for (int t = 0; t < NT; ++t) {
    const int d = t & 1;
    const bool st_a = (t + 1 < NT);
    const bool st_b = (t + 2 < NT);

    PHASE(0, 0, true,
          { if (st_a) { STAGE_A(d ^ 1, 0, t + 1); STAGE_A(d ^ 1, 1, t + 1); } },
          {});
    PHASE(1, 0, false, {}, {});
    PHASE(0, 1, true, {}, {});
    PHASE(1, 1, false,
          { if (st_b) { STAGE_B(d, 0, t + 2); STAGE_B(d, 1, t + 2); } },
          { if (st_b) { asm volatile("s_waitcnt vmcnt(4)" ::: "memory"); }
            else      { asm volatile("s_waitcnt vmcnt(0)" ::: "memory"); } });
  }
#undef PHASE
#undef STAGE_B
#undef STAGE_A

  // epilogue: C/D layout col = lane&15, row = (lane>>4)*4 + r
  const int row0 = ti * 256 + wm * 128;
  const int col0 = tj * 256 + wn * 64;
  const float* bp = bias0;
  if constexpr (MODE == 0) bp = (tj < 4) ? bias0 : ((tj < 8) ? bias1 : bias2);
#pragma unroll
  for (int m = 0; m < 8; ++m) {
#pragma unroll
    for (int n = 0; n < 4; ++n) {
#pragma unroll
      for (int r = 0; r < 4; ++r) {
        const int gr = row0 + m * 16 + (lane >> 4) * 4 + r;
        const int gc = col0 + n * 16 + (lane & 15);
        const float v = acc[m][n][r];
        if constexpr (MODE == 0) {
          ((unsigned short*)C)[(size_t)gr * CLD + gc] = f2bf(v + bp[gc & 1023]);
        } else {
          ((float*)C)[(size_t)gr * CLD + gc] = v + bp[gc];
        }
      }
    }
  }
}

// ============== 128x128 tri-buffered GEMM (R3 engine, scores/PV) =============
// MODE 2: scores: per-batch triangular grid; A=Q sec, B=K sec of QKVb (ld 3072)
// MODE 3: PV: per-batch, A=P[b][2048,2048], B=Vt[b][1024,2048], K truncated
template<int MODE>
__global__ __launch_bounds__(256, 3)
void gemm_kernel(const unsigned short* __restrict__ A,
                 const unsigned short* __restrict__ B,
                 void* __restrict__ C)
{
  __shared__ unsigned short As[3][128 * 32];
  __shared__ unsigned short Bs[3][128 * 32];

  const int tid  = threadIdx.x;
  const int wave = tid >> 6;
  const int lane = tid & 63;
  const int wr   = wave >> 1;
  const int wc   = wave & 1;

  const unsigned short *Ab, *Bb;
  int lda, ldb, ktiles;
  int ti, tj, bz = 0;

  if constexpr (MODE == 2) {
    int t = blockIdx.x; bz = blockIdx.y;
    ti = 0;
    while ((ti + 1) * (ti + 2) / 2 <= t) ++ti;   // triangular decode
    tj = t - ti * (ti + 1) / 2;                  // tj <= ti
    Ab = A + (size_t)bz * SDIM * QKVN + (size_t)ti * 128 * QKVN;        lda = QKVN; // Q
    Bb = A + (size_t)bz * SDIM * QKVN + (size_t)tj * 128 * QKVN + 1024; ldb = QKVN; // K
    ktiles = DDIM / 32;
  } else { // MODE 3
    bz = blockIdx.y;
    ti = blockIdx.x >> 3;
    tj = blockIdx.x & 7;
    Ab = A + (size_t)bz * SDIM * SDIM + (size_t)ti * 128 * SDIM; lda = SDIM;
    Bb = B + (size_t)bz * DDIM * SDIM + (size_t)tj * 128 * SDIM; ldb = SDIM;
    ktiles = (ti + 1) * 4;
  }

  f32x4 acc[4][4];
#pragma unroll
  for (int i = 0; i < 4; ++i)
#pragma unroll
    for (int j = 0; j < 4; ++j) acc[i][j] = (f32x4){0.f, 0.f, 0.f, 0.f};

  const int g0   = (lane & 7) ^ (lane >> 3);
  const int rloc = 2 * (lane >> 3) + (g0 >> 2);
  const int colg = (g0 & 3) * 8;

  const int s_  = lane >> 4;
  const int fr  = lane & 15;
  const int p_  = (((fr & 1) << 2) | s_) ^ ((fr >> 1) & 7);
  const int fA  = wr * 2048 + (fr >> 1) * 64 + p_ * 8;
  const int fB  = wc * 2048 + (fr >> 1) * 64 + p_ * 8;

#define STAGE(buf, kt) do {                                                     \
    const size_t kb_ = (size_t)(kt) * 32 + colg;                                \
    GLOAD16(Ab + (size_t)(wave * 16 + rloc) * lda + kb_,      &As[buf][wave * 512]);       \
    GLOAD16(Ab + (size_t)(64 + wave * 16 + rloc) * lda + kb_, &As[buf][(wave + 4) * 512]); \
    GLOAD16(Bb + (size_t)(wave * 16 + rloc) * ldb + kb_,      &Bs[buf][wave * 512]);       \
    GLOAD16(Bb + (size_t)(64 + wave * 16 + rloc) * ldb + kb_, &Bs[buf][(wave + 4) * 512]); \
  } while (0)

  STAGE(0, 0);
  STAGE(1, 1);
  asm volatile("s_waitcnt vmcnt(4)" ::: "memory");
  __builtin_amdgcn_s_barrier();
  __builtin_amdgcn_sched_barrier(0);

  for (int kt = 0; kt < ktiles; ++kt) {
    const int cur = kt % 3;
    if (kt + 2 < ktiles) STAGE((kt + 2) % 3, kt + 2);

    bf16x8 af[4], bfv[4];
#pragma unroll
    for (int mi = 0; mi < 4; ++mi)
      af[mi] = *reinterpret_cast<const bf16x8*>(&As[cur][fA + mi * 512]);
#pragma unroll
    for (int ni = 0; ni < 4; ++ni)
      bfv[ni] = *reinterpret_cast<const bf16x8*>(&Bs[cur][fB + ni * 512]);

    __builtin_amdgcn_s_setprio(1);
#pragma unroll
    for (int mi = 0; mi < 4; ++mi)
#pragma unroll
      for (int ni = 0; ni < 4; ++ni)
        acc[mi][ni] = __builtin_amdgcn_mfma_f32_16x16x32_bf16(af[mi], bfv[ni], acc[mi][ni], 0, 0, 0);
    __builtin_amdgcn_s_setprio(0);

    asm volatile("s_waitcnt vmcnt(4)" ::: "memory");
    __builtin_amdgcn_s_barrier();
    __builtin_amdgcn_sched_barrier(0);
  }
#undef STAGE

  const int row0 = wr * 64, col0 = wc * 64;
#pragma unroll
  for (int mi = 0; mi < 4; ++mi) {
#pragma unroll
    for (int ni = 0; ni < 4; ++ni) {
#pragma unroll
      for (int r = 0; r < 4; ++r) {
        const int lr = row0 + mi * 16 + (lane >> 4) * 4 + r;
        const int lc = col0 + ni * 16 + (lane & 15);
        const float v = acc[mi][ni][r];
        if constexpr (MODE == 2) {
          const int gi = ti * 128 + lr, gj = tj * 128 + lc;
          float s = fabsf(v) * 0.03125f;            // |q.k| / sqrt(1024)
          if (gj > gi) s = -INFINITY;               // strictly-above diag
          ((unsigned short*)C)[(size_t)bz * SDIM * SDIM + (size_t)gi * SDIM + gj] = f2bf(s);
        } else {
          const int gi = ti * 128 + lr, gd = tj * 128 + lc;
          ((unsigned short*)C)[(size_t)bz * SDIM * DDIM + (size_t)gi * DDIM + gd] = f2bf(v);
        }
      }
    }
  }
}

// ---------------- one-pass vectorized row softmax ----------------
__global__ void softmax_rows(unsigned short* __restrict__ Sc) {
  const int rid = blockIdx.x;
  const int b = rid >> 11, i = rid & (SDIM - 1);
  unsigned short* row = Sc + ((size_t)b * SDIM + i) * SDIM;
  const int Lpad = ((i >> 7) + 1) << 7;  // next 128 boundary (PV is 128-tiled)
  const int tid  = threadIdx.x;
  const bool act = tid * 8 < Lpad;

  float v[8];
  float m = 0.0f;
  if (act) {
    u16x8 u = *reinterpret_cast<const u16x8*>(row + tid * 8);
#pragma unroll
    for (int e = 0; e < 8; ++e) { v[e] = bf2f(u[e]); m = fmaxf(m, v[e]); }
  }
#pragma unroll
  for (int off = 32; off; off >>= 1) m = fmaxf(m, __shfl_down(m, off));
  __shared__ float redm[4], reds[4];
  if ((tid & 63) == 0) redm[tid >> 6] = m;
  __syncthreads();
  const float M = fmaxf(fmaxf(redm[0], redm[1]), fmaxf(redm[2], redm[3]));

  float s = 0.0f;
  if (act) {
#pragma unroll
    for (int e = 0; e < 8; ++e) { v[e] = expf(v[e] - M); s += v[e]; }
  }
#pragma unroll
  for (int off = 32; off; off >>= 1) s += __shfl_down(s, off);
  if ((tid & 63) == 0) reds[tid >> 6] = s;
  __syncthreads();
  const float inv = 1.0f / (reds[0] + reds[1] + reds[2] + reds[3]);

  if (act) {
    ushort4 o0, o1;
    o0.x = f2bf(v[0] * inv); o0.y = f2bf(v[1] * inv);
    o0.z = f2bf(v[2] * inv); o0.w = f2bf(v[3] * inv);
    o1.x = f2bf(v[4] * inv); o1.y = f2bf(v[5] * inv);
    o1.z = f2bf(v[6] * inv); o1.w = f2bf(v[7] * inv);
    *reinterpret_cast<ushort4*>(row + tid * 8)     = o0;
    *reinterpret_cast<ushort4*>(row + tid * 8 + 4) = o1;
  }
}

// ---------------- bf16 transpose: V section of QKVb -> Vt[B,1024,2048] -------
__global__ void transpose_v(const unsigned short* __restrict__ qkv,
                            unsigned short* __restrict__ out) {
  __shared__ unsigned short tile[64][65];
  const int b = blockIdx.z;
  const unsigned short* in = qkv + (size_t)b * SDIM * QKVN + 2048;  // V section
  unsigned short* o = out + (size_t)b * DDIM * SDIM;
  const int tx = threadIdx.x & 63;
  const int ty = threadIdx.x >> 6;
  const int r0 = blockIdx.y * 64;
  const int c0 = blockIdx.x * 64;
  for (int r = ty; r < 64; r += 4)
    tile[r][tx] = in[(size_t)(r0 + r) * QKVN + c0 + tx];
  __syncthreads();
  for (int r = ty; r < 64; r += 4)
    o[(size_t)(c0 + r) * SDIM + r0 + tx] = tile[tx][r];
}

// ---------------- host launch ----------------
extern "C" void kernel_launch(void* const* d_in, const int* in_sizes, int n_in,
                              void* d_out, int out_size, void* d_ws, size_t ws_size,
                              hipStream_t stream) {
  const float* x  = (const float*)d_in[0];
  const float* Wq = (const float*)d_in[1];
  const float* bq = (const float*)d_in[2];
  const float* Wk = (const float*)d_in[3];
  const float* bk = (const float*)d_in[4];
  const float* Wv = (const float*)d_in[5];
  const float* bv = (const float*)d_in[6];
  const float* Wo = (const float*)d_in[7];
  const float* bo = (const float*)d_in[8];
  float* out = (float*)d_out;

  const size_t NTOK = (size_t)BATCH * SDIM;       // 8192
  unsigned short* ws = (unsigned short*)d_ws;
  unsigned short* xb   = ws;                          // [8192,1024]
  unsigned short* wqkv = xb + NTOK * DDIM;            // [3072,1024]
  unsigned short* wo   = wqkv + (size_t)QKVN * DDIM;  // [1024,1024]
  unsigned short* QKVb = wo + (size_t)DDIM * DDIM;    // [8192,3072]
  unsigned short* Vt   = QKVb + NTOK * QKVN;          // [B,1024,2048]
  unsigned short* Ob   = Vt + NTOK * DDIM;            // [8192,1024]
  unsigned short* Sc   = Ob + NTOK * DDIM;            // [B,2048,2048]

  const int NX = (int)(NTOK * DDIM);              // 8M

  cvt_f32_bf16<<<2048, 256, 0, stream>>>(x, xb, NX);
  cvt_weights<<<dim3(256, 4), 256, 0, stream>>>(Wq, Wk, Wv, Wo, wqkv);

  // fused QKV projection -> QKVb [8192, 3072]   (32x12 = 384 blocks)
  gemm256<0><<<384, 512, 0, stream>>>(xb, wqkv, bq, bk, bv, QKVb);

  // scores (lower-triangular tiles): Sc = bf16(|Q@K^T|/32), -inf above diag
  gemm_kernel<2><<<dim3(136, BATCH), 256, 0, stream>>>(QKVb, nullptr, Sc);

  // one-pass softmax (in place; padding becomes exact 0)
  softmax_rows<<<BATCH * SDIM, 256, 0, stream>>>(Sc);

  // V transpose for NT PV gemm
  transpose_v<<<dim3(DDIM / 64, SDIM / 64, BATCH), 256, 0, stream>>>(QKVb, Vt);

  // O = P @ V (causal-truncated K)
  gemm_kernel<3><<<dim3(128, BATCH), 256, 0, stream>>>(Sc, Vt, Ob);

  // final projection -> fp32 out   (32x4 = 128 blocks)
  gemm256<1><<<128, 512, 0, stream>>>(Ob, wo, bo, nullptr, nullptr, out);
}